// Round 5
// baseline (337.709 us; speedup 1.0000x reference)
//
#include <hip/hip_runtime.h>
#include <hip/hip_bf16.h>
#include <math.h>

#define NN 4096
#define DD 256

typedef __bf16 bf16x8 __attribute__((ext_vector_type(8)));
typedef short  short8 __attribute__((ext_vector_type(8)));
typedef float  f32x4  __attribute__((ext_vector_type(4)));

#define MFMA16(a, b, c) __builtin_amdgcn_mfma_f32_16x16x32_bf16((a), (b), (c), 0, 0, 0)

__device__ inline bf16x8 brelu(bf16x8 a) {
    short8 s = __builtin_bit_cast(short8, a);
    s = s & ~(s >> 15);            // negative (sign bit set) -> 0, else keep
    return __builtin_bit_cast(bf16x8, s);
}

__device__ inline float wave_red(float v) {
#pragma unroll
    for (int o = 32; o > 0; o >>= 1) v += __shfl_down(v, o, 64);
    return v;
}

__device__ inline unsigned short bfbits(float f) {
    return __builtin_bit_cast(unsigned short, (__bf16)f);
}

// =====================================================================================
// k_pre: fused preprocessing. blockIdx.x ranges:
//   [0,4096)        conv_t row
//   [4096,8192)     conv_s row (scatter via LDS)
//   [8192,8704)     cur/pre -> bf16 transpose tiles (curT/preT)
//   [8704,8752)     proj conversions: spa^T, tmp^T, theta (48 = 3 mats x 16 tiles)
//   [8752,9520)     small GEMMs (self-converting): z0 -> -master_s, z1 -> -master_t, z2 -> nodeFea
// =====================================================================================
__global__ __launch_bounds__(256) void k_pre(
    const float* __restrict__ cur, const float* __restrict__ pre,
    const float* __restrict__ r_proj_s, const float* __restrict__ inc_s,
    const float* __restrict__ r_proj_t, const float* __restrict__ inc_t,
    const float* __restrict__ node_pj, const float* __restrict__ spa_pj,
    const float* __restrict__ tmp_pj, const float* __restrict__ theta_w,
    __bf16* __restrict__ Mt, __bf16* __restrict__ Ms,
    __bf16* __restrict__ curT, __bf16* __restrict__ preT,
    __bf16* __restrict__ pTspa, __bf16* __restrict__ pTtmp, __bf16* __restrict__ thetaBf,
    float* __restrict__ negMs, float* __restrict__ negMt, float* __restrict__ nodeFea,
    float* __restrict__ rsT, float* __restrict__ rsS,
    float* __restrict__ pAbsT, float* __restrict__ pSqT,
    float* __restrict__ pAbsS, float* __restrict__ pSqS)
{
    __shared__ __align__(16) char sm[18496];
    const int bx = blockIdx.x, t = threadIdx.x;

    if (bx < 8192) {
        // ---------------- incidence conversion ----------------
        float (*red)[4] = (float(*)[4])(sm + 8192 + 64);
        float rs = 0.f, as = 0.f, qs = 0.f;
        const int w = t >> 6, lane = t & 63;
        if (bx < 4096) {
            const int i = bx;
            const float4* src = (const float4*)(inc_t + (size_t)i * NN);
            ushort4* dst = (ushort4*)(Mt + (size_t)i * NN);
#pragma unroll
            for (int e = 0; e < 4; ++e) {
                const int f = t + 256 * e;
                float4 v = src[f];
                float x[4] = {v.x, v.y, v.z, v.w};
                unsigned short o[4];
#pragma unroll
                for (int j = 0; j < 4; ++j) {
                    float fv = x[j];
                    as += fabsf(fv); qs += fv * fv; rs += fmaxf(fv, 0.f);
                    o[j] = bfbits(fv);
                }
                dst[f] = make_ushort4(o[0], o[1], o[2], o[3]);
            }
            rs = wave_red(rs); as = wave_red(as); qs = wave_red(qs);
            if (lane == 0) { red[0][w] = rs; red[1][w] = as; red[2][w] = qs; }
            __syncthreads();
            if (t == 0) {
                rsT[i]   = red[0][0] + red[0][1] + red[0][2] + red[0][3];
                pAbsT[i] = red[1][0] + red[1][1] + red[1][2] + red[1][3];
                pSqT[i]  = red[2][0] + red[2][1] + red[2][2] + red[2][3];
            }
        } else {
            const int i = bx - 4096;
            unsigned short* row = (unsigned short*)sm;     // 8KB staging
            const float* srow = inc_s + (size_t)i * (NN - 1);
#pragma unroll
            for (int e = 0; e < 4; ++e) {
                const int f = t + 256 * e;
                float x[4] = {0.f, 0.f, 0.f, 0.f};
                if (f < 1023) __builtin_memcpy(x, srow + 4 * f, 16);
                else          __builtin_memcpy(x, srow + 4092, 12);
#pragma unroll
                for (int j = 0; j < 4; ++j) {
                    const int k = 4 * f + j;
                    float fv = x[j];
                    as += fabsf(fv); qs += fv * fv; rs += fmaxf(fv, 0.f);
                    if (k < NN - 1) row[k + (k >= i)] = bfbits(fv);
                }
            }
            if (t == 0) row[i] = 0;
            __syncthreads();
            uint4* dOut = (uint4*)(Ms + (size_t)i * NN);
            const uint4* sIn = (const uint4*)row;
            dOut[t] = sIn[t];
            dOut[t + 256] = sIn[t + 256];
            rs = wave_red(rs); as = wave_red(as); qs = wave_red(qs);
            if (lane == 0) { red[0][w] = rs; red[1][w] = as; red[2][w] = qs; }
            __syncthreads();
            if (t == 0) {
                rsS[i]   = red[0][0] + red[0][1] + red[0][2] + red[0][3];
                pAbsS[i] = red[1][0] + red[1][1] + red[1][2] + red[1][3];
                pSqS[i]  = red[2][0] + red[2][1] + red[2][2] + red[2][3];
            }
        }
    } else if (bx < 8704) {
        // ---------------- cur/pre transpose tiles ----------------
        const int idx = bx - 8192;
        const int z = idx >> 8, yt = (idx >> 6) & 3, xt = idx & 63;
        const int i0 = xt * 64, d0 = yt * 64;
        const float* src = z ? pre : cur;
        __bf16* dstT = z ? preT : curT;
        unsigned short (*tile)[72] = (unsigned short(*)[72])sm;
        const int r = t >> 2, c4 = (t & 3) * 16;
        const float* srow = src + (size_t)(i0 + r) * DD + d0 + c4;
        alignas(16) unsigned short loc[16];
#pragma unroll
        for (int e = 0; e < 4; ++e) {
            float4 v = ((const float4*)srow)[e];
            loc[e * 4 + 0] = bfbits(v.x); loc[e * 4 + 1] = bfbits(v.y);
            loc[e * 4 + 2] = bfbits(v.z); loc[e * 4 + 3] = bfbits(v.w);
        }
#pragma unroll
        for (int e = 0; e < 16; ++e) tile[r][c4 + e] = loc[e];
        __syncthreads();
        alignas(16) unsigned short o[16];
#pragma unroll
        for (int e = 0; e < 16; ++e) o[e] = tile[c4 + e][r];
        __bf16* trow = dstT + (size_t)(d0 + r) * NN + i0 + c4;
        *(uint4*)trow = *(uint4*)&o[0];
        *(uint4*)(trow + 8) = *(uint4*)&o[8];
    } else if (bx < 8752) {
        // ---------------- projection matrix conversions ----------------
        const int idx = bx - 8704;
        const int m = idx >> 4, tt = idx & 15;
        const int k0 = (tt >> 2) * 64, n0 = (tt & 3) * 64;
        const int r = t >> 2, c4 = (t & 3) * 16;
        if (m < 2) {
            const float* src = m == 0 ? spa_pj : tmp_pj;
            __bf16* dst = m == 0 ? pTspa : pTtmp;
            unsigned short (*tile)[72] = (unsigned short(*)[72])sm;
            const float* srow = src + (size_t)(k0 + r) * DD + n0 + c4;
            alignas(16) unsigned short loc[16];
#pragma unroll
            for (int e = 0; e < 4; ++e) {
                float4 v = ((const float4*)srow)[e];
                loc[e * 4 + 0] = bfbits(v.x); loc[e * 4 + 1] = bfbits(v.y);
                loc[e * 4 + 2] = bfbits(v.z); loc[e * 4 + 3] = bfbits(v.w);
            }
#pragma unroll
            for (int e = 0; e < 16; ++e) tile[r][c4 + e] = loc[e];
            __syncthreads();
            alignas(16) unsigned short o[16];
#pragma unroll
            for (int e = 0; e < 16; ++e) o[e] = tile[c4 + e][r];
            __bf16* trow = dst + (size_t)(n0 + r) * DD + k0 + c4;
            *(uint4*)trow = *(uint4*)&o[0];
            *(uint4*)(trow + 8) = *(uint4*)&o[8];
        } else {
            // theta: direct convert, [j][k] layout already is B^T
            const float* srow = theta_w + (size_t)(k0 + r) * DD + n0 + c4;
            alignas(16) unsigned short loc[16];
#pragma unroll
            for (int e = 0; e < 4; ++e) {
                float4 v = ((const float4*)srow)[e];
                loc[e * 4 + 0] = bfbits(v.x); loc[e * 4 + 1] = bfbits(v.y);
                loc[e * 4 + 2] = bfbits(v.z); loc[e * 4 + 3] = bfbits(v.w);
            }
            __bf16* drow = thetaBf + (size_t)(k0 + r) * DD + n0 + c4;
            *(uint4*)drow = *(uint4*)&loc[0];
            *(uint4*)(drow + 8) = *(uint4*)&loc[8];
        }
    } else {
        // ---------------- small GEMMs (self-converting from fp32 inputs) ----------------
        const int idx = bx - 8752;
        const int z = idx >> 8, r2 = idx & 255;
        const int n0 = (r2 & 3) * 64, m0 = (r2 >> 2) * 64;
        const float* srcB = z == 0 ? r_proj_s : (z == 1 ? r_proj_t : node_pj);
        __bf16 (*As)[72] = (__bf16(*)[72])sm;
        __bf16 (*Bs)[72] = (__bf16(*)[72])(sm + 9232);
        f32x4 acc[2][2];
#pragma unroll
        for (int i = 0; i < 2; ++i)
#pragma unroll
            for (int j = 0; j < 2; ++j) acc[i][j] = (f32x4)0.f;
        const int w = t >> 6, lane = t & 63, quad = lane >> 4, l16 = lane & 15;
        const int wr = w >> 1, wc = w & 1;
        const int sr = t >> 2, sc = (t & 3) * 16;
        for (int kt = 0; kt < 4; ++kt) {
            const int k0 = kt * 64;
            alignas(16) __bf16 av[16], bv[16];
            const float* arow = cur + (size_t)(m0 + sr) * DD + k0 + sc;
#pragma unroll
            for (int e4 = 0; e4 < 4; ++e4) {
                float4 v = ((const float4*)arow)[e4];
                av[e4 * 4 + 0] = (__bf16)v.x; av[e4 * 4 + 1] = (__bf16)v.y;
                av[e4 * 4 + 2] = (__bf16)v.z; av[e4 * 4 + 3] = (__bf16)v.w;
            }
#pragma unroll
            for (int e = 0; e < 16; ++e)
                bv[e] = (__bf16)srcB[(size_t)(k0 + sc + e) * DD + n0 + sr];   // B^T gather
            __syncthreads();
            *(uint4*)&As[sr][sc] = *(uint4*)&av[0]; *(uint4*)&As[sr][sc + 8] = *(uint4*)&av[8];
            *(uint4*)&Bs[sr][sc] = *(uint4*)&bv[0]; *(uint4*)&Bs[sr][sc + 8] = *(uint4*)&bv[8];
            __syncthreads();
#pragma unroll
            for (int ks = 0; ks < 2; ++ks) {
                const int kc = ks * 32 + quad * 8;
                bf16x8 a0 = *(const bf16x8*)&As[wr * 32 + l16][kc];
                bf16x8 a1 = *(const bf16x8*)&As[wr * 32 + 16 + l16][kc];
                bf16x8 b0 = *(const bf16x8*)&Bs[wc * 32 + l16][kc];
                bf16x8 b1 = *(const bf16x8*)&Bs[wc * 32 + 16 + l16][kc];
                acc[0][0] = MFMA16(a0, b0, acc[0][0]);
                acc[0][1] = MFMA16(a0, b1, acc[0][1]);
                acc[1][0] = MFMA16(a1, b0, acc[1][0]);
                acc[1][1] = MFMA16(a1, b1, acc[1][1]);
            }
        }
#pragma unroll
        for (int mi = 0; mi < 2; ++mi)
#pragma unroll
            for (int ni = 0; ni < 2; ++ni)
#pragma unroll
                for (int r = 0; r < 4; ++r) {
                    int gr = m0 + wr * 32 + mi * 16 + quad * 4 + r;
                    int gc = n0 + wc * 32 + ni * 16 + l16;
                    size_t o = (size_t)gr * DD + gc;
                    float v = acc[mi][ni][r];
                    if (z == 0) negMs[o] = -v;
                    else if (z == 1) negMt[o] = -v;
                    else nodeFea[o] = v;
                }
    }
}

// =====================================================================================
// k_big: dual GEMM (raw + relu) — 32-row x 256-col stripe, 8 waves, BK=128 dbuf LDS(A),
// XOR-swizzled (conflict-free), direct-global B with 1-step register prefetch.
// =====================================================================================
__global__ __launch_bounds__(512) void k_big(const __bf16* __restrict__ Mt, const __bf16* __restrict__ Ms,
                                             const __bf16* __restrict__ preT, const __bf16* __restrict__ curT,
                                             const float* __restrict__ negMt, const float* __restrict__ negMs,
                                             const float* __restrict__ cur,
                                             float* __restrict__ feaT, float* __restrict__ feaS,
                                             float* __restrict__ pDiff) {
    const int z = blockIdx.y;
    const __bf16* A  = z ? Ms : Mt;
    const __bf16* BT = z ? curT : preT;
    const float* negM = z ? negMs : negMt;
    float* fea = z ? feaS : feaT;
    const int m0 = blockIdx.x * 32;
    __shared__ __bf16 As[2][32 * 128];      // 16KB, XOR-swizzled 16-elem blocks
    __shared__ float sred[8];
    const int t = threadIdx.x, w = t >> 6, lane = t & 63, quad = lane >> 4, l16 = lane & 15;
    const int wr = w >> 2, wc = w & 3;      // wave: 16 m-rows x 64 n-cols
    // staging map: 512 threads x 16B = 8KB = 32 rows x 128 k
    const int srow = t >> 4, c8 = t & 15;
    const int scb = c8 >> 1, shalf = c8 & 1;
    const int sofs = srow * 128 + ((scb ^ (srow & 7)) << 4) + shalf * 8;
    const __bf16* gA = A + (size_t)(m0 + srow) * NN + c8 * 8;
    const int nb = wc * 64;
    const __bf16* gB0 = BT + (size_t)(nb + l16) * NN + quad * 8;
    const int arow = wr * 16 + l16;
    const int abase = arow * 128;
    const int asw = arow & 7;

    f32x4 accR[4], accL[4];
#pragma unroll
    for (int nf = 0; nf < 4; ++nf) { accR[nf] = (f32x4)0.f; accL[nf] = (f32x4)0.f; }

    uint4 pA = *(const uint4*)gA; gA += 128;
    *(uint4*)&As[0][sofs] = pA;
    pA = *(const uint4*)gA; gA += 128;
    __syncthreads();

    for (int kt = 0; kt < 32; ++kt) {
        const int cb = kt & 1;
        if (kt < 31) {
            *(uint4*)&As[cb ^ 1][sofs] = pA;
            if (kt < 30) { pA = *(const uint4*)gA; gA += 128; }
        }
        const size_t kgl = (size_t)kt * 128;
        bf16x8 b[4], bn[4];
#pragma unroll
        for (int nf = 0; nf < 4; ++nf)
            b[nf] = *(const bf16x8*)(gB0 + (size_t)nf * 16 * NN + kgl);
#pragma unroll
        for (int ks = 0; ks < 4; ++ks) {
            if (ks < 3) {
#pragma unroll
                for (int nf = 0; nf < 4; ++nf)
                    bn[nf] = *(const bf16x8*)(gB0 + (size_t)nf * 16 * NN + kgl + (ks + 1) * 32);
            }
            const int acb = ks * 2 + (quad >> 1);
            bf16x8 a = *(const bf16x8*)&As[cb][abase + ((acb ^ asw) << 4) + (quad & 1) * 8];
            bf16x8 ar = brelu(a);
#pragma unroll
            for (int nf = 0; nf < 4; ++nf) {
                accR[nf] = MFMA16(a, b[nf], accR[nf]);
                accL[nf] = MFMA16(ar, b[nf], accL[nf]);
            }
            if (ks < 3) {
#pragma unroll
                for (int nf = 0; nf < 4; ++nf) b[nf] = bn[nf];
            }
        }
        __syncthreads();
    }
    float sumd = 0.f;
#pragma unroll
    for (int nf = 0; nf < 4; ++nf)
#pragma unroll
        for (int r = 0; r < 4; ++r) {
            int gr = m0 + wr * 16 + quad * 4 + r;
            int gc = nb + nf * 16 + l16;
            size_t idx = (size_t)gr * DD + gc;
            float diff = accR[nf][r] + negM[idx];     // recon - master
            sumd += diff * diff;
            fea[idx] = accL[nf][r] + cur[idx];        // relu-product + cur
        }
    sumd = wave_red(sumd);
    if (lane == 0) sred[w] = sumd;
    __syncthreads();
    if (t == 0) {
        float s = 0.f;
#pragma unroll
        for (int i = 0; i < 8; ++i) s += sred[i];
        pDiff[z * 128 + blockIdx.x] = s;
    }
}

// ---------------- shared MFMA inner step for the 64x64-tile kernels ----------------
__device__ inline void mfma_step0(const __bf16 (*As)[72], const __bf16 (*Bs)[72],
                                  int wr, int wc, int quad, int l16, f32x4 (&acc)[2][2]) {
#pragma unroll
    for (int ks = 0; ks < 2; ++ks) {
        const int kc = ks * 32 + quad * 8;
        bf16x8 a0 = *(const bf16x8*)&As[wr * 32 + l16][kc];
        bf16x8 a1 = *(const bf16x8*)&As[wr * 32 + 16 + l16][kc];
        bf16x8 b0 = *(const bf16x8*)&Bs[wc * 32 + l16][kc];
        bf16x8 b1 = *(const bf16x8*)&Bs[wc * 32 + 16 + l16][kc];
        acc[0][0] = MFMA16(a0, b0, acc[0][0]);
        acc[0][1] = MFMA16(a0, b1, acc[0][1]);
        acc[1][0] = MFMA16(a1, b0, acc[1][0]);
        acc[1][1] = MFMA16(a1, b1, acc[1][1]);
    }
}

// ---------------- edge-feature projections: spa_fea / tmp_fea ----------------
__global__ __launch_bounds__(256) void k_fea(const float* __restrict__ feaS, const float* __restrict__ feaT,
                                             const float* __restrict__ rsS, const float* __restrict__ rsT,
                                             const __bf16* __restrict__ pTspa, const __bf16* __restrict__ pTtmp,
                                             float* __restrict__ spaF, float* __restrict__ tmpF) {
    const int z = blockIdx.z;
    const float* fea = z ? feaT : feaS;
    const float* rs = z ? rsT : rsS;
    const __bf16* BT = z ? pTtmp : pTspa;
    float* outF = z ? tmpF : spaF;
    const int n0 = blockIdx.x * 64, m0 = blockIdx.y * 64;
    __shared__ __bf16 As[64][72], Bs[64][72];
    f32x4 acc[2][2];
#pragma unroll
    for (int i = 0; i < 2; ++i)
#pragma unroll
        for (int j = 0; j < 2; ++j) acc[i][j] = (f32x4)0.f;
    const int t = threadIdx.x, w = t >> 6, lane = t & 63, quad = lane >> 4, l16 = lane & 15;
    const int wr = w >> 1, wc = w & 1;
    const int sr = t >> 2, sc = (t & 3) * 16;
    const float inv = 1.f / (rs[m0 + sr] + 1.f);
    const float* gA = fea + (size_t)(m0 + sr) * DD + sc;
    const __bf16* gB = BT + (size_t)(n0 + sr) * DD + sc;
    for (int kt = 0; kt < DD / 64; ++kt) {
        __bf16 tmp[16];
#pragma unroll
        for (int e4 = 0; e4 < 4; ++e4) {
            float4 v = ((const float4*)gA)[e4];
            tmp[e4 * 4 + 0] = (__bf16)(v.x * inv);
            tmp[e4 * 4 + 1] = (__bf16)(v.y * inv);
            tmp[e4 * 4 + 2] = (__bf16)(v.z * inv);
            tmp[e4 * 4 + 3] = (__bf16)(v.w * inv);
        }
        uint4 bv0 = *(const uint4*)(gB);
        uint4 bv1 = *(const uint4*)(gB + 8);
        __syncthreads();
        *(uint4*)&As[sr][sc] = *(uint4*)&tmp[0]; *(uint4*)&As[sr][sc + 8] = *(uint4*)&tmp[8];
        *(uint4*)&Bs[sr][sc] = bv0; *(uint4*)&Bs[sr][sc + 8] = bv1;
        __syncthreads();
        mfma_step0(As, Bs, wr, wc, quad, l16, acc);
        gA += 64; gB += 64;
    }
#pragma unroll
    for (int mi = 0; mi < 2; ++mi)
#pragma unroll
        for (int ni = 0; ni < 2; ++ni)
#pragma unroll
            for (int r = 0; r < 4; ++r) {
                int gr = m0 + wr * 32 + mi * 16 + quad * 4 + r;
                int gc = n0 + wc * 32 + ni * 16 + l16;
                outF[(size_t)gr * DD + gc] = acc[mi][ni][r];
            }
}

// ---------------- attention scalars ----------------
__global__ __launch_bounds__(256) void k_attn(const float* __restrict__ spaF, const float* __restrict__ tmpF,
                                              const float* __restrict__ nodeF,
                                              float* __restrict__ spaA, float* __restrict__ tmpA) {
    const int t = threadIdx.x, w = t >> 6, lane = t & 63;
    const int i = blockIdx.x * 4 + w;
    const float4* sf = (const float4*)(spaF + (size_t)i * DD);
    const float4* tf = (const float4*)(tmpF + (size_t)i * DD);
    const float4* nf = (const float4*)(nodeF + (size_t)i * DD);
    float4 s = sf[lane], p = tf[lane], n = nf[lane];
    float ds = s.x * n.x + s.y * n.y + s.z * n.z + s.w * n.w;
    float dt = p.x * n.x + p.y * n.y + p.z * n.z + p.w * n.w;
    ds = wave_red(ds); dt = wave_red(dt);
    if (lane == 0) { spaA[i] = ds * 0.0625f; tmpA[i] = dt * 0.0625f; }  // 1/sqrt(256)
}

// ---------------- final: val @ theta_w^T + b, relu -> d_out ----------------
__global__ __launch_bounds__(256) void k_final(const float* __restrict__ spaF, const float* __restrict__ tmpF,
                                               const float* __restrict__ spaA, const float* __restrict__ tmpA,
                                               const __bf16* __restrict__ thetaBf, const float* __restrict__ thetaB,
                                               float* __restrict__ out) {
    const int n0 = blockIdx.x * 64, m0 = blockIdx.y * 64;
    __shared__ __bf16 As[64][72], Bs[64][72];
    f32x4 acc[2][2];
#pragma unroll
    for (int i = 0; i < 2; ++i)
#pragma unroll
        for (int j = 0; j < 2; ++j) acc[i][j] = (f32x4)0.f;
    const int t = threadIdx.x, w = t >> 6, lane = t & 63, quad = lane >> 4, l16 = lane & 15;
    const int wr = w >> 1, wc = w & 1;
    const int sr = t >> 2, sc = (t & 3) * 16;
    const float sa = spaA[m0 + sr], ta = tmpA[m0 + sr];
    const float* gS = spaF + (size_t)(m0 + sr) * DD + sc;
    const float* gT = tmpF + (size_t)(m0 + sr) * DD + sc;
    const __bf16* gB = thetaBf + (size_t)(n0 + sr) * DD + sc;
    for (int kt = 0; kt < DD / 64; ++kt) {
        __bf16 tmp[16];
#pragma unroll
        for (int e4 = 0; e4 < 4; ++e4) {
            float4 vs = ((const float4*)gS)[e4];
            float4 vt = ((const float4*)gT)[e4];
            tmp[e4 * 4 + 0] = (__bf16)(sa * vs.x + ta * vt.x);
            tmp[e4 * 4 + 1] = (__bf16)(sa * vs.y + ta * vt.y);
            tmp[e4 * 4 + 2] = (__bf16)(sa * vs.z + ta * vt.z);
            tmp[e4 * 4 + 3] = (__bf16)(sa * vs.w + ta * vt.w);
        }
        uint4 bv0 = *(const uint4*)(gB);
        uint4 bv1 = *(const uint4*)(gB + 8);
        __syncthreads();
        *(uint4*)&As[sr][sc] = *(uint4*)&tmp[0]; *(uint4*)&As[sr][sc + 8] = *(uint4*)&tmp[8];
        *(uint4*)&Bs[sr][sc] = bv0; *(uint4*)&Bs[sr][sc + 8] = bv1;
        __syncthreads();
        mfma_step0(As, Bs, wr, wc, quad, l16, acc);
        gS += 64; gT += 64; gB += 64;
    }
#pragma unroll
    for (int mi = 0; mi < 2; ++mi)
#pragma unroll
        for (int ni = 0; ni < 2; ++ni)
#pragma unroll
            for (int r = 0; r < 4; ++r) {
                int gr = m0 + wr * 32 + mi * 16 + quad * 4 + r;
                int gc = n0 + wc * 32 + ni * 16 + l16;
                float v = acc[mi][ni][r] + thetaB[gc];
                out[(size_t)gr * DD + gc] = fmaxf(v, 0.f);
            }
}

// ---------------- loss: reduce per-block partials, single block ----------------
__global__ __launch_bounds__(256) void k_loss(const float* __restrict__ pAbsT, const float* __restrict__ pSqT,
                                              const float* __restrict__ pAbsS, const float* __restrict__ pSqS,
                                              const float* __restrict__ pDiff,
                                              float* __restrict__ out) {
    const int t = threadIdx.x;
    float aT = 0.f, qT = 0.f, aS = 0.f, qS = 0.f;
#pragma unroll
    for (int j = 0; j < 16; ++j) {
        const int i = t + 256 * j;
        aT += pAbsT[i]; qT += pSqT[i]; aS += pAbsS[i]; qS += pSqS[i];
    }
    float pd = pDiff[t];
    float dT = t < 128 ? pd : 0.f;
    float dS = t < 128 ? 0.f : pd;
    aT = wave_red(aT); qT = wave_red(qT); aS = wave_red(aS); qS = wave_red(qS);
    dT = wave_red(dT); dS = wave_red(dS);
    __shared__ float red[6][4];
    const int w = t >> 6, lane = t & 63;
    if (lane == 0) { red[0][w] = aT; red[1][w] = qT; red[2][w] = aS; red[3][w] = qS; red[4][w] = dT; red[5][w] = dS; }
    __syncthreads();
    if (t == 0) {
        float s[6];
#pragma unroll
        for (int k = 0; k < 6; ++k) s[k] = red[k][0] + red[k][1] + red[k][2] + red[k][3];
        float l = s[0] + 0.001f * sqrtf(s[1]) + 0.2f * sqrtf(s[4])    // temporal
                + s[2] + 0.001f * sqrtf(s[3]) + 0.2f * sqrtf(s[5]);   // spatial
        out[(size_t)NN * DD] = l;
    }
}

extern "C" void kernel_launch(void* const* d_in, const int* in_sizes, int n_in,
                              void* d_out, int out_size, void* d_ws, size_t ws_size,
                              hipStream_t stream) {
    (void)in_sizes; (void)n_in; (void)out_size; (void)ws_size;
    const float* cur      = (const float*)d_in[0];
    const float* pre      = (const float*)d_in[1];
    const float* r_proj_s = (const float*)d_in[2];
    const float* inc_s    = (const float*)d_in[3];
    const float* r_proj_t = (const float*)d_in[4];
    const float* inc_t    = (const float*)d_in[5];
    const float* node_pj  = (const float*)d_in[6];
    const float* spa_pj   = (const float*)d_in[7];
    const float* tmp_pj   = (const float*)d_in[8];
    const float* theta_w  = (const float*)d_in[9];
    const float* theta_b  = (const float*)d_in[10];
    float* out = (float*)d_out;

    char* p = (char*)d_ws;
    auto alloc = [&](size_t bytes) -> void* {
        void* r = (void*)p;
        p += (bytes + 255) & ~(size_t)255;
        return r;
    };
    __bf16* Mt      = (__bf16*)alloc((size_t)NN * NN * 2);
    __bf16* Ms      = (__bf16*)alloc((size_t)NN * NN * 2);
    __bf16* curT    = (__bf16*)alloc((size_t)NN * DD * 2);
    __bf16* preT    = (__bf16*)alloc((size_t)NN * DD * 2);
    __bf16* pTspa   = (__bf16*)alloc((size_t)DD * DD * 2);
    __bf16* pTtmp   = (__bf16*)alloc((size_t)DD * DD * 2);
    __bf16* thetaBf = (__bf16*)alloc((size_t)DD * DD * 2);
    float* negMs    = (float*)alloc((size_t)NN * DD * 4);
    float* negMt    = (float*)alloc((size_t)NN * DD * 4);
    float* nodeFea  = (float*)alloc((size_t)NN * DD * 4);
    float* feaS     = (float*)alloc((size_t)NN * DD * 4);
    float* feaT     = (float*)alloc((size_t)NN * DD * 4);
    float* spaF     = (float*)alloc((size_t)NN * DD * 4);
    float* tmpF     = (float*)alloc((size_t)NN * DD * 4);
    float* rsS      = (float*)alloc((size_t)NN * 4);
    float* rsT      = (float*)alloc((size_t)NN * 4);
    float* spaA     = (float*)alloc((size_t)NN * 4);
    float* tmpA     = (float*)alloc((size_t)NN * 4);
    float* pAbsT    = (float*)alloc((size_t)NN * 4);
    float* pSqT     = (float*)alloc((size_t)NN * 4);
    float* pAbsS    = (float*)alloc((size_t)NN * 4);
    float* pSqS     = (float*)alloc((size_t)NN * 4);
    float* pDiff    = (float*)alloc(256 * 4);

    k_pre<<<9520, 256, 0, stream>>>(cur, pre, r_proj_s, inc_s, r_proj_t, inc_t,
                                    node_pj, spa_pj, tmp_pj, theta_w,
                                    Mt, Ms, curT, preT, pTspa, pTtmp, thetaBf,
                                    negMs, negMt, nodeFea,
                                    rsT, rsS, pAbsT, pSqT, pAbsS, pSqS);
    k_big<<<dim3(128, 2), 512, 0, stream>>>(Mt, Ms, preT, curT, negMt, negMs, cur, feaT, feaS, pDiff);
    k_fea<<<dim3(4, 64, 2), 256, 0, stream>>>(feaS, feaT, rsS, rsT, pTspa, pTtmp, spaF, tmpF);
    k_attn<<<NN / 4, 256, 0, stream>>>(spaF, tmpF, nodeFea, spaA, tmpA);
    k_final<<<dim3(4, 64), 256, 0, stream>>>(spaF, tmpF, spaA, tmpA, thetaBf, theta_b, out);
    k_loss<<<1, 256, 0, stream>>>(pAbsT, pSqT, pAbsS, pSqS, pDiff, out);
}

// Round 6
// 272.365 us; speedup vs baseline: 1.2399x; 1.2399x over previous
//
#include <hip/hip_runtime.h>
#include <hip/hip_bf16.h>
#include <math.h>

#define NN 4096
#define DD 256

typedef __bf16 bf16x8 __attribute__((ext_vector_type(8)));
typedef short  short8 __attribute__((ext_vector_type(8)));
typedef float  f32x4  __attribute__((ext_vector_type(4)));

#define MFMA16(a, b, c) __builtin_amdgcn_mfma_f32_16x16x32_bf16((a), (b), (c), 0, 0, 0)

__device__ inline bf16x8 brelu(bf16x8 a) {
    short8 s = __builtin_bit_cast(short8, a);
    s = s & ~(s >> 15);            // negative (sign bit set) -> 0, else keep
    return __builtin_bit_cast(bf16x8, s);
}

__device__ inline float wave_red(float v) {
#pragma unroll
    for (int o = 32; o > 0; o >>= 1) v += __shfl_down(v, o, 64);
    return v;
}

__device__ inline unsigned short bfbits(float f) {
    return __builtin_bit_cast(unsigned short, (__bf16)f);
}

// async global->LDS, 16B per lane, lds dest = uniform base + lane*16
#define GLL16(g, l) __builtin_amdgcn_global_load_lds( \
    (const __attribute__((address_space(1))) void*)(g), \
    (__attribute__((address_space(3))) void*)(l), 16, 0, 0)

// =====================================================================================
// k_pre: fused preprocessing. blockIdx.x ranges:
//   [0,4096)        conv_t row        [4096,8192)  conv_s row (LDS scatter)
//   [8192,8704)     cur/pre bf16 (+T) tiles (cur_bf/curT/preT)
//   [8704,8800)     proj conversions: 6 mats x 16 tiles (5 transposed + theta direct)
// =====================================================================================
__global__ __launch_bounds__(256) void k_pre(
    const float* __restrict__ cur, const float* __restrict__ pre,
    const float* __restrict__ r_proj_s, const float* __restrict__ inc_s,
    const float* __restrict__ r_proj_t, const float* __restrict__ inc_t,
    const float* __restrict__ node_pj, const float* __restrict__ spa_pj,
    const float* __restrict__ tmp_pj, const float* __restrict__ theta_w,
    __bf16* __restrict__ Mt, __bf16* __restrict__ Ms,
    __bf16* __restrict__ cur_bf, __bf16* __restrict__ curT, __bf16* __restrict__ preT,
    __bf16* __restrict__ pTs, __bf16* __restrict__ pTt, __bf16* __restrict__ pTn,
    __bf16* __restrict__ pTspa, __bf16* __restrict__ pTtmp, __bf16* __restrict__ thetaBf,
    float* __restrict__ rsT, float* __restrict__ rsS,
    float* __restrict__ pAbsT, float* __restrict__ pSqT,
    float* __restrict__ pAbsS, float* __restrict__ pSqS)
{
    __shared__ __align__(16) char sm[9280];
    const int bx = blockIdx.x, t = threadIdx.x;

    if (bx < 8192) {
        float (*red)[4] = (float(*)[4])(sm + 8192 + 16);
        float rs = 0.f, as = 0.f, qs = 0.f;
        const int w = t >> 6, lane = t & 63;
        if (bx < 4096) {
            const int i = bx;
            const float4* src = (const float4*)(inc_t + (size_t)i * NN);
            ushort4* dst = (ushort4*)(Mt + (size_t)i * NN);
#pragma unroll
            for (int e = 0; e < 4; ++e) {
                const int f = t + 256 * e;
                float4 v = src[f];
                float x[4] = {v.x, v.y, v.z, v.w};
                unsigned short o[4];
#pragma unroll
                for (int j = 0; j < 4; ++j) {
                    float fv = x[j];
                    as += fabsf(fv); qs += fv * fv; rs += fmaxf(fv, 0.f);
                    o[j] = bfbits(fv);
                }
                dst[f] = make_ushort4(o[0], o[1], o[2], o[3]);
            }
            rs = wave_red(rs); as = wave_red(as); qs = wave_red(qs);
            if (lane == 0) { red[0][w] = rs; red[1][w] = as; red[2][w] = qs; }
            __syncthreads();
            if (t == 0) {
                rsT[i]   = red[0][0] + red[0][1] + red[0][2] + red[0][3];
                pAbsT[i] = red[1][0] + red[1][1] + red[1][2] + red[1][3];
                pSqT[i]  = red[2][0] + red[2][1] + red[2][2] + red[2][3];
            }
        } else {
            const int i = bx - 4096;
            unsigned short* row = (unsigned short*)sm;     // 8KB scatter staging
            const float* srow = inc_s + (size_t)i * (NN - 1);
#pragma unroll
            for (int e = 0; e < 4; ++e) {
                const int f = t + 256 * e;
                float x[4] = {0.f, 0.f, 0.f, 0.f};
                if (f < 1023) __builtin_memcpy(x, srow + 4 * f, 16);
                else          __builtin_memcpy(x, srow + 4092, 12);
#pragma unroll
                for (int j = 0; j < 4; ++j) {
                    const int k = 4 * f + j;
                    float fv = x[j];
                    as += fabsf(fv); qs += fv * fv; rs += fmaxf(fv, 0.f);
                    if (k < NN - 1) row[k + (k >= i)] = bfbits(fv);
                }
            }
            if (t == 0) row[i] = 0;
            __syncthreads();
            uint4* dOut = (uint4*)(Ms + (size_t)i * NN);
            const uint4* sIn = (const uint4*)row;
            dOut[t] = sIn[t];
            dOut[t + 256] = sIn[t + 256];
            rs = wave_red(rs); as = wave_red(as); qs = wave_red(qs);
            if (lane == 0) { red[0][w] = rs; red[1][w] = as; red[2][w] = qs; }
            __syncthreads();
            if (t == 0) {
                rsS[i]   = red[0][0] + red[0][1] + red[0][2] + red[0][3];
                pAbsS[i] = red[1][0] + red[1][1] + red[1][2] + red[1][3];
                pSqS[i]  = red[2][0] + red[2][1] + red[2][2] + red[2][3];
            }
        }
    } else if (bx < 8704) {
        const int idx = bx - 8192;
        const int z = idx >> 8, yt = (idx >> 6) & 3, xt = idx & 63;
        const int i0 = xt * 64, d0 = yt * 64;
        const float* src = z ? pre : cur;
        __bf16* dstT = z ? preT : curT;
        unsigned short (*tile)[72] = (unsigned short(*)[72])sm;
        const int r = t >> 2, c4 = (t & 3) * 16;
        const float* srow = src + (size_t)(i0 + r) * DD + d0 + c4;
        alignas(16) unsigned short loc[16];
#pragma unroll
        for (int e = 0; e < 4; ++e) {
            float4 v = ((const float4*)srow)[e];
            loc[e * 4 + 0] = bfbits(v.x); loc[e * 4 + 1] = bfbits(v.y);
            loc[e * 4 + 2] = bfbits(v.z); loc[e * 4 + 3] = bfbits(v.w);
        }
#pragma unroll
        for (int e = 0; e < 16; ++e) tile[r][c4 + e] = loc[e];
        if (z == 0) {
            __bf16* drow = cur_bf + (size_t)(i0 + r) * DD + d0 + c4;
            *(uint4*)drow = *(uint4*)&loc[0];
            *(uint4*)(drow + 8) = *(uint4*)&loc[8];
        }
        __syncthreads();
        alignas(16) unsigned short o[16];
#pragma unroll
        for (int e = 0; e < 16; ++e) o[e] = tile[c4 + e][r];
        __bf16* trow = dstT + (size_t)(d0 + r) * NN + i0 + c4;
        *(uint4*)trow = *(uint4*)&o[0];
        *(uint4*)(trow + 8) = *(uint4*)&o[8];
    } else {
        const int idx = bx - 8704;
        const int m = idx >> 4, tt = idx & 15;
        const int k0 = (tt >> 2) * 64, n0 = (tt & 3) * 64;
        const int r = t >> 2, c4 = (t & 3) * 16;
        const float* src = m == 0 ? r_proj_s : m == 1 ? r_proj_t : m == 2 ? node_pj
                         : m == 3 ? spa_pj : m == 4 ? tmp_pj : theta_w;
        __bf16* dst = m == 0 ? pTs : m == 1 ? pTt : m == 2 ? pTn
                    : m == 3 ? pTspa : m == 4 ? pTtmp : thetaBf;
        const float* srow = src + (size_t)(k0 + r) * DD + n0 + c4;
        alignas(16) unsigned short loc[16];
#pragma unroll
        for (int e = 0; e < 4; ++e) {
            float4 v = ((const float4*)srow)[e];
            loc[e * 4 + 0] = bfbits(v.x); loc[e * 4 + 1] = bfbits(v.y);
            loc[e * 4 + 2] = bfbits(v.z); loc[e * 4 + 3] = bfbits(v.w);
        }
        if (m < 5) {
            unsigned short (*tile)[72] = (unsigned short(*)[72])sm;
#pragma unroll
            for (int e = 0; e < 16; ++e) tile[r][c4 + e] = loc[e];
            __syncthreads();
            alignas(16) unsigned short o[16];
#pragma unroll
            for (int e = 0; e < 16; ++e) o[e] = tile[c4 + e][r];
            __bf16* trow = dst + (size_t)(n0 + r) * DD + k0 + c4;
            *(uint4*)trow = *(uint4*)&o[0];
            *(uint4*)(trow + 8) = *(uint4*)&o[8];
        } else {
            __bf16* drow = dst + (size_t)(k0 + r) * DD + n0 + c4;
            *(uint4*)drow = *(uint4*)&loc[0];
            *(uint4*)(drow + 8) = *(uint4*)&loc[8];
        }
    }
}

// =====================================================================================
// k_big: dual GEMM, 64x64 tiles, grid (4n, 64m, 2z). A+B staged via global_load_lds
// (async, dbuf); XOR swizzle via global-address permutation -> conflict-free ds_read_b128.
// =====================================================================================
__global__ __launch_bounds__(256) void k_big(const __bf16* __restrict__ Mt, const __bf16* __restrict__ Ms,
                                             const __bf16* __restrict__ preT, const __bf16* __restrict__ curT,
                                             const float* __restrict__ negMt, const float* __restrict__ negMs,
                                             const float* __restrict__ cur,
                                             float* __restrict__ feaT, float* __restrict__ feaS,
                                             float* __restrict__ pDiff) {
    const int z = blockIdx.z;
    const __bf16* A  = z ? Ms : Mt;        // [4096][4096]
    const __bf16* BT = z ? curT : preT;    // [256][4096]
    const float* negM = z ? negMs : negMt;
    float* fea = z ? feaS : feaT;
    const int n0 = blockIdx.x * 64, m0 = blockIdx.y * 64;
    __shared__ __align__(16) char smA[2 * 8192];
    __shared__ __align__(16) char smB[2 * 8192];
    __shared__ float sred[4];
    const int t = threadIdx.x, w = t >> 6, lane = t & 63, quad = lane >> 4, l16 = lane & 15;
    const int wr = w >> 1, wc = w & 1;

    // ---- staging address map: lane -> (row lr, kb lk), global kb pre-XOR-swizzled ----
    const int lr = lane >> 3, lk = lane & 7;
    const int kswz = (lk ^ lr) << 3;                       // swizzled k-elem offset
    const __bf16* gA0 = A + (size_t)(m0 + w * 16 + lr) * NN + kswz;
    const __bf16* gA1 = A + (size_t)(m0 + w * 16 + 8 + lr) * NN + kswz;
    const __bf16* gB0 = BT + (size_t)(n0 + w * 16 + lr) * NN + kswz;
    const __bf16* gB1 = BT + (size_t)(n0 + w * 16 + 8 + lr) * NN + kswz;
    char* lA0 = smA + (w * 16) * 128;
    char* lA1 = smA + (w * 16 + 8) * 128;
    char* lB0 = smB + (w * 16) * 128;
    char* lB1 = smB + (w * 16 + 8) * 128;

#define STAGE(bo, kt) do { const size_t ko = (size_t)(kt) * 64; \
        GLL16(gA0 + ko, lA0 + (bo)); GLL16(gA1 + ko, lA1 + (bo)); \
        GLL16(gB0 + ko, lB0 + (bo)); GLL16(gB1 + ko, lB1 + (bo)); } while (0)

    f32x4 accR[2][2], accL[2][2];
#pragma unroll
    for (int i = 0; i < 2; ++i)
#pragma unroll
        for (int j = 0; j < 2; ++j) { accR[i][j] = (f32x4)0.f; accL[i][j] = (f32x4)0.f; }

    // ---- compute-side LDS offsets (swizzled reads: slot = kb ^ (row&7)) ----
    const int s7 = l16 & 7;
    const int aoff0 = (wr * 32 + l16) * 128;           // row mi=0
    const int boff0 = (wc * 32 + l16) * 128;

    STAGE(0, 0);
    __syncthreads();

#pragma unroll 2
    for (int kt = 0; kt < 64; ++kt) {
        const int cb = (kt & 1) * 8192;
        if (kt < 63) STAGE(cb ^ 8192, kt + 1);         // async into other buffer
        const char* Ab = smA + cb;
        const char* Bb = smB + cb;
#pragma unroll
        for (int ks = 0; ks < 2; ++ks) {
            const int slot = ((ks * 4 + quad) ^ s7) << 4;
            bf16x8 a0 = *(const bf16x8*)(Ab + aoff0 + slot);
            bf16x8 a1 = *(const bf16x8*)(Ab + aoff0 + 2048 + slot);
            bf16x8 b0 = *(const bf16x8*)(Bb + boff0 + slot);
            bf16x8 b1 = *(const bf16x8*)(Bb + boff0 + 2048 + slot);
            bf16x8 a0r = brelu(a0), a1r = brelu(a1);
            accR[0][0] = MFMA16(a0, b0, accR[0][0]);
            accR[0][1] = MFMA16(a0, b1, accR[0][1]);
            accR[1][0] = MFMA16(a1, b0, accR[1][0]);
            accR[1][1] = MFMA16(a1, b1, accR[1][1]);
            accL[0][0] = MFMA16(a0r, b0, accL[0][0]);
            accL[0][1] = MFMA16(a0r, b1, accL[0][1]);
            accL[1][0] = MFMA16(a1r, b0, accL[1][0]);
            accL[1][1] = MFMA16(a1r, b1, accL[1][1]);
        }
        __syncthreads();   // drains this iter's async stage (flew during compute)
    }
#undef STAGE

    float sumd = 0.f;
#pragma unroll
    for (int mi = 0; mi < 2; ++mi)
#pragma unroll
        for (int ni = 0; ni < 2; ++ni)
#pragma unroll
            for (int r = 0; r < 4; ++r) {
                int gr = m0 + wr * 32 + mi * 16 + quad * 4 + r;
                int gc = n0 + wc * 32 + ni * 16 + l16;
                size_t idx = (size_t)gr * DD + gc;
                float diff = accR[mi][ni][r] + negM[idx];   // recon - master
                sumd += diff * diff;
                fea[idx] = accL[mi][ni][r] + cur[idx];      // relu-product + cur
            }
    sumd = wave_red(sumd);
    if (lane == 0) sred[w] = sumd;
    __syncthreads();
    if (t == 0)
        pDiff[z * 256 + blockIdx.y * 4 + blockIdx.x] = sred[0] + sred[1] + sred[2] + sred[3];
}

// ---------------- shared MFMA inner step for the 64x64-tile small kernels ----------------
__device__ inline void mfma_step0(const __bf16 (*As)[72], const __bf16 (*Bs)[72],
                                  int wr, int wc, int quad, int l16, f32x4 (&acc)[2][2]) {
#pragma unroll
    for (int ks = 0; ks < 2; ++ks) {
        const int kc = ks * 32 + quad * 8;
        bf16x8 a0 = *(const bf16x8*)&As[wr * 32 + l16][kc];
        bf16x8 a1 = *(const bf16x8*)&As[wr * 32 + 16 + l16][kc];
        bf16x8 b0 = *(const bf16x8*)&Bs[wc * 32 + l16][kc];
        bf16x8 b1 = *(const bf16x8*)&Bs[wc * 32 + 16 + l16][kc];
        acc[0][0] = MFMA16(a0, b0, acc[0][0]);
        acc[0][1] = MFMA16(a0, b1, acc[0][1]);
        acc[1][0] = MFMA16(a1, b0, acc[1][0]);
        acc[1][1] = MFMA16(a1, b1, acc[1][1]);
    }
}

// ---------------- small GEMMs: -master_s, -master_t, node_fea ----------------
__global__ __launch_bounds__(256) void k_small3(const __bf16* __restrict__ cur_bf,
                                                const __bf16* __restrict__ pTs, const __bf16* __restrict__ pTt,
                                                const __bf16* __restrict__ pTn,
                                                float* __restrict__ negMs, float* __restrict__ negMt,
                                                float* __restrict__ nodeFea) {
    const int z = blockIdx.z;
    const __bf16* BT = z == 0 ? pTs : (z == 1 ? pTt : pTn);
    const int n0 = blockIdx.x * 64, m0 = blockIdx.y * 64;
    __shared__ __bf16 As[64][72], Bs[64][72];
    f32x4 acc[2][2];
#pragma unroll
    for (int i = 0; i < 2; ++i)
#pragma unroll
        for (int j = 0; j < 2; ++j) acc[i][j] = (f32x4)0.f;
    const int t = threadIdx.x, w = t >> 6, lane = t & 63, quad = lane >> 4, l16 = lane & 15;
    const int wr = w >> 1, wc = w & 1;
    const int sr = t >> 2, sc = (t & 3) * 16;
    const __bf16* gA = cur_bf + (size_t)(m0 + sr) * DD + sc;
    const __bf16* gB = BT + (size_t)(n0 + sr) * DD + sc;
    for (int kt = 0; kt < DD / 64; ++kt) {
        uint4 av0 = *(const uint4*)(gA);
        uint4 av1 = *(const uint4*)(gA + 8);
        uint4 bv0 = *(const uint4*)(gB);
        uint4 bv1 = *(const uint4*)(gB + 8);
        __syncthreads();
        *(uint4*)&As[sr][sc] = av0; *(uint4*)&As[sr][sc + 8] = av1;
        *(uint4*)&Bs[sr][sc] = bv0; *(uint4*)&Bs[sr][sc + 8] = bv1;
        __syncthreads();
        mfma_step0(As, Bs, wr, wc, quad, l16, acc);
        gA += 64; gB += 64;
    }
#pragma unroll
    for (int mi = 0; mi < 2; ++mi)
#pragma unroll
        for (int ni = 0; ni < 2; ++ni)
#pragma unroll
            for (int r = 0; r < 4; ++r) {
                int gr = m0 + wr * 32 + mi * 16 + quad * 4 + r;
                int gc = n0 + wc * 32 + ni * 16 + l16;
                size_t o = (size_t)gr * DD + gc;
                float v = acc[mi][ni][r];
                if (z == 0) negMs[o] = -v;
                else if (z == 1) negMt[o] = -v;
                else nodeFea[o] = v;
            }
}

// ---------------- edge-feature projections: spa_fea / tmp_fea ----------------
__global__ __launch_bounds__(256) void k_fea(const float* __restrict__ feaS, const float* __restrict__ feaT,
                                             const float* __restrict__ rsS, const float* __restrict__ rsT,
                                             const __bf16* __restrict__ pTspa, const __bf16* __restrict__ pTtmp,
                                             float* __restrict__ spaF, float* __restrict__ tmpF) {
    const int z = blockIdx.z;
    const float* fea = z ? feaT : feaS;
    const float* rs = z ? rsT : rsS;
    const __bf16* BT = z ? pTtmp : pTspa;
    float* outF = z ? tmpF : spaF;
    const int n0 = blockIdx.x * 64, m0 = blockIdx.y * 64;
    __shared__ __bf16 As[64][72], Bs[64][72];
    f32x4 acc[2][2];
#pragma unroll
    for (int i = 0; i < 2; ++i)
#pragma unroll
        for (int j = 0; j < 2; ++j) acc[i][j] = (f32x4)0.f;
    const int t = threadIdx.x, w = t >> 6, lane = t & 63, quad = lane >> 4, l16 = lane & 15;
    const int wr = w >> 1, wc = w & 1;
    const int sr = t >> 2, sc = (t & 3) * 16;
    const float inv = 1.f / (rs[m0 + sr] + 1.f);
    const float* gA = fea + (size_t)(m0 + sr) * DD + sc;
    const __bf16* gB = BT + (size_t)(n0 + sr) * DD + sc;
    for (int kt = 0; kt < DD / 64; ++kt) {
        __bf16 tmp[16];
#pragma unroll
        for (int e4 = 0; e4 < 4; ++e4) {
            float4 v = ((const float4*)gA)[e4];
            tmp[e4 * 4 + 0] = (__bf16)(v.x * inv);
            tmp[e4 * 4 + 1] = (__bf16)(v.y * inv);
            tmp[e4 * 4 + 2] = (__bf16)(v.z * inv);
            tmp[e4 * 4 + 3] = (__bf16)(v.w * inv);
        }
        uint4 bv0 = *(const uint4*)(gB);
        uint4 bv1 = *(const uint4*)(gB + 8);
        __syncthreads();
        *(uint4*)&As[sr][sc] = *(uint4*)&tmp[0]; *(uint4*)&As[sr][sc + 8] = *(uint4*)&tmp[8];
        *(uint4*)&Bs[sr][sc] = bv0; *(uint4*)&Bs[sr][sc + 8] = bv1;
        __syncthreads();
        mfma_step0(As, Bs, wr, wc, quad, l16, acc);
        gA += 64; gB += 64;
    }
#pragma unroll
    for (int mi = 0; mi < 2; ++mi)
#pragma unroll
        for (int ni = 0; ni < 2; ++ni)
#pragma unroll
            for (int r = 0; r < 4; ++r) {
                int gr = m0 + wr * 32 + mi * 16 + quad * 4 + r;
                int gc = n0 + wc * 32 + ni * 16 + l16;
                outF[(size_t)gr * DD + gc] = acc[mi][ni][r];
            }
}

// ---------------- attention scalars ----------------
__global__ __launch_bounds__(256) void k_attn(const float* __restrict__ spaF, const float* __restrict__ tmpF,
                                              const float* __restrict__ nodeF,
                                              float* __restrict__ spaA, float* __restrict__ tmpA) {
    const int t = threadIdx.x, w = t >> 6, lane = t & 63;
    const int i = blockIdx.x * 4 + w;
    const float4* sf = (const float4*)(spaF + (size_t)i * DD);
    const float4* tf = (const float4*)(tmpF + (size_t)i * DD);
    const float4* nf = (const float4*)(nodeF + (size_t)i * DD);
    float4 s = sf[lane], p = tf[lane], n = nf[lane];
    float ds = s.x * n.x + s.y * n.y + s.z * n.z + s.w * n.w;
    float dt = p.x * n.x + p.y * n.y + p.z * n.z + p.w * n.w;
    ds = wave_red(ds); dt = wave_red(dt);
    if (lane == 0) { spaA[i] = ds * 0.0625f; tmpA[i] = dt * 0.0625f; }  // 1/sqrt(256)
}

// ---------------- final: val @ theta_w^T + b, relu -> d_out ----------------
__global__ __launch_bounds__(256) void k_final(const float* __restrict__ spaF, const float* __restrict__ tmpF,
                                               const float* __restrict__ spaA, const float* __restrict__ tmpA,
                                               const __bf16* __restrict__ thetaBf, const float* __restrict__ thetaB,
                                               float* __restrict__ out) {
    const int n0 = blockIdx.x * 64, m0 = blockIdx.y * 64;
    __shared__ __bf16 As[64][72], Bs[64][72];
    f32x4 acc[2][2];
#pragma unroll
    for (int i = 0; i < 2; ++i)
#pragma unroll
        for (int j = 0; j < 2; ++j) acc[i][j] = (f32x4)0.f;
    const int t = threadIdx.x, w = t >> 6, lane = t & 63, quad = lane >> 4, l16 = lane & 15;
    const int wr = w >> 1, wc = w & 1;
    const int sr = t >> 2, sc = (t & 3) * 16;
    const float sa = spaA[m0 + sr], ta = tmpA[m0 + sr];
    const float* gS = spaF + (size_t)(m0 + sr) * DD + sc;
    const float* gT = tmpF + (size_t)(m0 + sr) * DD + sc;
    const __bf16* gB = thetaBf + (size_t)(n0 + sr) * DD + sc;
    for (int kt = 0; kt < DD / 64; ++kt) {
        __bf16 tmp[16];
#pragma unroll
        for (int e4 = 0; e4 < 4; ++e4) {
            float4 vs = ((const float4*)gS)[e4];
            float4 vt = ((const float4*)gT)[e4];
            tmp[e4 * 4 + 0] = (__bf16)(sa * vs.x + ta * vt.x);
            tmp[e4 * 4 + 1] = (__bf16)(sa * vs.y + ta * vt.y);
            tmp[e4 * 4 + 2] = (__bf16)(sa * vs.z + ta * vt.z);
            tmp[e4 * 4 + 3] = (__bf16)(sa * vs.w + ta * vt.w);
        }
        uint4 bv0 = *(const uint4*)(gB);
        uint4 bv1 = *(const uint4*)(gB + 8);
        __syncthreads();
        *(uint4*)&As[sr][sc] = *(uint4*)&tmp[0]; *(uint4*)&As[sr][sc + 8] = *(uint4*)&tmp[8];
        *(uint4*)&Bs[sr][sc] = bv0; *(uint4*)&Bs[sr][sc + 8] = bv1;
        __syncthreads();
        mfma_step0(As, Bs, wr, wc, quad, l16, acc);
        gS += 64; gT += 64; gB += 64;
    }
#pragma unroll
    for (int mi = 0; mi < 2; ++mi)
#pragma unroll
        for (int ni = 0; ni < 2; ++ni)
#pragma unroll
            for (int r = 0; r < 4; ++r) {
                int gr = m0 + wr * 32 + mi * 16 + quad * 4 + r;
                int gc = n0 + wc * 32 + ni * 16 + l16;
                float v = acc[mi][ni][r] + thetaB[gc];
                out[(size_t)gr * DD + gc] = fmaxf(v, 0.f);
            }
}

// ---------------- loss: reduce per-block partials, single block ----------------
__global__ __launch_bounds__(256) void k_loss(const float* __restrict__ pAbsT, const float* __restrict__ pSqT,
                                              const float* __restrict__ pAbsS, const float* __restrict__ pSqS,
                                              const float* __restrict__ pDiff,
                                              float* __restrict__ out) {
    const int t = threadIdx.x;
    float aT = 0.f, qT = 0.f, aS = 0.f, qS = 0.f;
#pragma unroll
    for (int j = 0; j < 16; ++j) {
        const int i = t + 256 * j;
        aT += pAbsT[i]; qT += pSqT[i]; aS += pAbsS[i]; qS += pSqS[i];
    }
    float dT = pDiff[t], dS = pDiff[256 + t];
    aT = wave_red(aT); qT = wave_red(qT); aS = wave_red(aS); qS = wave_red(qS);
    dT = wave_red(dT); dS = wave_red(dS);
    __shared__ float red[6][4];
    const int w = t >> 6, lane = t & 63;
    if (lane == 0) { red[0][w] = aT; red[1][w] = qT; red[2][w] = aS; red[3][w] = qS; red[4][w] = dT; red[5][w] = dS; }
    __syncthreads();
    if (t == 0) {
        float s[6];
#pragma unroll
        for (int k = 0; k < 6; ++k) s[k] = red[k][0] + red[k][1] + red[k][2] + red[k][3];
        float l = s[0] + 0.001f * sqrtf(s[1]) + 0.2f * sqrtf(s[4])    // temporal
                + s[2] + 0.001f * sqrtf(s[3]) + 0.2f * sqrtf(s[5]);   // spatial
        out[(size_t)NN * DD] = l;
    }
}

extern "C" void kernel_launch(void* const* d_in, const int* in_sizes, int n_in,
                              void* d_out, int out_size, void* d_ws, size_t ws_size,
                              hipStream_t stream) {
    (void)in_sizes; (void)n_in; (void)out_size; (void)ws_size;
    const float* cur      = (const float*)d_in[0];
    const float* pre      = (const float*)d_in[1];
    const float* r_proj_s = (const float*)d_in[2];
    const float* inc_s    = (const float*)d_in[3];
    const float* r_proj_t = (const float*)d_in[4];
    const float* inc_t    = (const float*)d_in[5];
    const float* node_pj  = (const float*)d_in[6];
    const float* spa_pj   = (const float*)d_in[7];
    const float* tmp_pj   = (const float*)d_in[8];
    const float* theta_w  = (const float*)d_in[9];
    const float* theta_b  = (const float*)d_in[10];
    float* out = (float*)d_out;

    char* p = (char*)d_ws;
    auto alloc = [&](size_t bytes) -> void* {
        void* r = (void*)p;
        p += (bytes + 255) & ~(size_t)255;
        return r;
    };
    __bf16* Mt      = (__bf16*)alloc((size_t)NN * NN * 2);
    __bf16* Ms      = (__bf16*)alloc((size_t)NN * NN * 2);
    __bf16* cur_bf  = (__bf16*)alloc((size_t)NN * DD * 2);
    __bf16* curT    = (__bf16*)alloc((size_t)NN * DD * 2);
    __bf16* preT    = (__bf16*)alloc((size_t)NN * DD * 2);
    __bf16* pTs     = (__bf16*)alloc((size_t)DD * DD * 2);
    __bf16* pTt     = (__bf16*)alloc((size_t)DD * DD * 2);
    __bf16* pTn     = (__bf16*)alloc((size_t)DD * DD * 2);
    __bf16* pTspa   = (__bf16*)alloc((size_t)DD * DD * 2);
    __bf16* pTtmp   = (__bf16*)alloc((size_t)DD * DD * 2);
    __bf16* thetaBf = (__bf16*)alloc((size_t)DD * DD * 2);
    float* negMs    = (float*)alloc((size_t)NN * DD * 4);
    float* negMt    = (float*)alloc((size_t)NN * DD * 4);
    float* nodeFea  = (float*)alloc((size_t)NN * DD * 4);
    float* feaS     = (float*)alloc((size_t)NN * DD * 4);
    float* feaT     = (float*)alloc((size_t)NN * DD * 4);
    float* spaF     = (float*)alloc((size_t)NN * DD * 4);
    float* tmpF     = (float*)alloc((size_t)NN * DD * 4);
    float* rsS      = (float*)alloc((size_t)NN * 4);
    float* rsT      = (float*)alloc((size_t)NN * 4);
    float* spaA     = (float*)alloc((size_t)NN * 4);
    float* tmpA     = (float*)alloc((size_t)NN * 4);
    float* pAbsT    = (float*)alloc((size_t)NN * 4);
    float* pSqT     = (float*)alloc((size_t)NN * 4);
    float* pAbsS    = (float*)alloc((size_t)NN * 4);
    float* pSqS     = (float*)alloc((size_t)NN * 4);
    float* pDiff    = (float*)alloc(512 * 4);

    k_pre<<<8800, 256, 0, stream>>>(cur, pre, r_proj_s, inc_s, r_proj_t, inc_t,
                                    node_pj, spa_pj, tmp_pj, theta_w,
                                    Mt, Ms, cur_bf, curT, preT,
                                    pTs, pTt, pTn, pTspa, pTtmp, thetaBf,
                                    rsT, rsS, pAbsT, pSqT, pAbsS, pSqS);
    k_small3<<<dim3(4, 64, 3), 256, 0, stream>>>(cur_bf, pTs, pTt, pTn, negMs, negMt, nodeFea);
    k_big<<<dim3(4, 64, 2), 256, 0, stream>>>(Mt, Ms, preT, curT, negMt, negMs, cur, feaT, feaS, pDiff);
    k_fea<<<dim3(4, 64, 2), 256, 0, stream>>>(feaS, feaT, rsS, rsT, pTspa, pTtmp, spaF, tmpF);
    k_attn<<<NN / 4, 256, 0, stream>>>(spaF, tmpF, nodeFea, spaA, tmpA);
    k_final<<<dim3(4, 64), 256, 0, stream>>>(spaF, tmpF, spaA, tmpA, thetaBf, theta_b, out);
    k_loss<<<1, 256, 0, stream>>>(pAbsT, pSqT, pAbsS, pSqS, pDiff, out);
}

// Round 7
// 271.465 us; speedup vs baseline: 1.2440x; 1.0033x over previous
//
#include <hip/hip_runtime.h>
#include <hip/hip_bf16.h>
#include <math.h>

#define NN 4096
#define DD 256

typedef __bf16 bf16x8 __attribute__((ext_vector_type(8)));
typedef short  short8 __attribute__((ext_vector_type(8)));
typedef float  f32x4  __attribute__((ext_vector_type(4)));

#define MFMA16(a, b, c) __builtin_amdgcn_mfma_f32_16x16x32_bf16((a), (b), (c), 0, 0, 0)

__device__ inline bf16x8 brelu(bf16x8 a) {
    short8 s = __builtin_bit_cast(short8, a);
    s = s & ~(s >> 15);            // negative (sign bit set) -> 0, else keep
    return __builtin_bit_cast(bf16x8, s);
}

__device__ inline float wave_red(float v) {
#pragma unroll
    for (int o = 32; o > 0; o >>= 1) v += __shfl_down(v, o, 64);
    return v;
}

__device__ inline unsigned short bfbits(float f) {
    return __builtin_bit_cast(unsigned short, (__bf16)f);
}

// ---------------- incidence_t -> bf16 + rowsum(relu) + per-row |x|, x^2 partials ----------------
__global__ __launch_bounds__(256) void k_conv_t(const float* __restrict__ inc,
                                                __bf16* __restrict__ Mbf,
                                                float* __restrict__ rowsum,
                                                float* __restrict__ pAbs, float* __restrict__ pSq) {
    const int i = blockIdx.x, t = threadIdx.x;
    const float4* src = (const float4*)(inc + (size_t)i * NN);
    ushort4* dst = (ushort4*)(Mbf + (size_t)i * NN);
    float rs = 0.f, as = 0.f, qs = 0.f;
#pragma unroll
    for (int e = 0; e < 4; ++e) {
        const int f = t + 256 * e;
        float4 v = src[f];
        float x[4] = {v.x, v.y, v.z, v.w};
        unsigned short o[4];
#pragma unroll
        for (int j = 0; j < 4; ++j) {
            float fv = x[j];
            as += fabsf(fv); qs += fv * fv; rs += fmaxf(fv, 0.f);
            o[j] = bfbits(fv);
        }
        dst[f] = make_ushort4(o[0], o[1], o[2], o[3]);
    }
    __shared__ float red[3][4];
    const int w = t >> 6, lane = t & 63;
    rs = wave_red(rs); as = wave_red(as); qs = wave_red(qs);
    if (lane == 0) { red[0][w] = rs; red[1][w] = as; red[2][w] = qs; }
    __syncthreads();
    if (t == 0) {
        rowsum[i] = red[0][0] + red[0][1] + red[0][2] + red[0][3];
        pAbs[i]   = red[1][0] + red[1][1] + red[1][2] + red[1][3];
        pSq[i]    = red[2][0] + red[2][1] + red[2][2] + red[2][3];
    }
}

// ---------------- incidence_s: shifted direct write (diagonal scatter = 1-elem shift) ----------------
__global__ __launch_bounds__(256) void k_conv_s(const float* __restrict__ inc,
                                                __bf16* __restrict__ Mbf,
                                                float* __restrict__ rowsum,
                                                float* __restrict__ pAbs, float* __restrict__ pSq) {
    const int i = blockIdx.x, t = threadIdx.x;
    const float* srow = inc + (size_t)i * (NN - 1);
    // sums over input domain [0, 4095)
    float xs[16];
    if (t < 255) __builtin_memcpy(xs, srow + 16 * t, 64);
    else { __builtin_memcpy(xs, srow + 16 * t, 60); xs[15] = 0.f; }
    float rs = 0.f, as = 0.f, qs = 0.f;
#pragma unroll
    for (int e = 0; e < 16; ++e) {
        float fv = xs[e];
        as += fabsf(fv); qs += fv * fv; rs += fmaxf(fv, 0.f);
    }
    // output chunk [16t, 16t+16): out[j] = (j==i) ? 0 : in[j - (j>i)]
    const int base = 16 * t;
    alignas(16) __bf16 o[16];
    if (i >= base + 16) {                 // all j < i : src = in[j] == xs
#pragma unroll
        for (int e = 0; e < 16; ++e) o[e] = (__bf16)xs[e];
    } else if (i < base) {                // all j > i : src = in[j-1]
        float ys[16];
        __builtin_memcpy(ys, srow + base - 1, 64);
#pragma unroll
        for (int e = 0; e < 16; ++e) o[e] = (__bf16)ys[e];
    } else {                              // straddle (one thread per block)
#pragma unroll
        for (int e = 0; e < 16; ++e) {
            const int j = base + e;
            o[e] = (j == i) ? (__bf16)0.f : (__bf16)srow[j - (j > i)];
        }
    }
    __bf16* drow = Mbf + (size_t)i * NN + base;
    *(uint4*)drow = *(uint4*)&o[0];
    *(uint4*)(drow + 8) = *(uint4*)&o[8];
    __shared__ float red[3][4];
    const int w = t >> 6, lane = t & 63;
    rs = wave_red(rs); as = wave_red(as); qs = wave_red(qs);
    if (lane == 0) { red[0][w] = rs; red[1][w] = as; red[2][w] = qs; }
    __syncthreads();
    if (t == 0) {
        rowsum[i] = red[0][0] + red[0][1] + red[0][2] + red[0][3];
        pAbs[i]   = red[1][0] + red[1][1] + red[1][2] + red[1][3];
        pSq[i]    = red[2][0] + red[2][1] + red[2][2] + red[2][3];
    }
}

// ---------------- misc: cur/pre bf16(+T) tiles [0,512), proj conversions [512,608) ----------------
__global__ __launch_bounds__(256) void k_misc(
    const float* __restrict__ cur, const float* __restrict__ pre,
    const float* __restrict__ r_proj_s, const float* __restrict__ r_proj_t,
    const float* __restrict__ node_pj, const float* __restrict__ spa_pj,
    const float* __restrict__ tmp_pj, const float* __restrict__ theta_w,
    __bf16* __restrict__ cur_bf, __bf16* __restrict__ curT, __bf16* __restrict__ preT,
    __bf16* __restrict__ pTs, __bf16* __restrict__ pTt, __bf16* __restrict__ pTn,
    __bf16* __restrict__ pTspa, __bf16* __restrict__ pTtmp, __bf16* __restrict__ thetaBf)
{
    __shared__ unsigned short tile[64][72];
    const int bx = blockIdx.x, t = threadIdx.x;
    const int r = t >> 2, c4 = (t & 3) * 16;
    if (bx < 512) {
        const int z = bx >> 8, yt = (bx >> 6) & 3, xt = bx & 63;
        const int i0 = xt * 64, d0 = yt * 64;
        const float* src = z ? pre : cur;
        __bf16* dstT = z ? preT : curT;
        const float* srow = src + (size_t)(i0 + r) * DD + d0 + c4;
        alignas(16) unsigned short loc[16];
#pragma unroll
        for (int e = 0; e < 4; ++e) {
            float4 v = ((const float4*)srow)[e];
            loc[e * 4 + 0] = bfbits(v.x); loc[e * 4 + 1] = bfbits(v.y);
            loc[e * 4 + 2] = bfbits(v.z); loc[e * 4 + 3] = bfbits(v.w);
        }
#pragma unroll
        for (int e = 0; e < 16; ++e) tile[r][c4 + e] = loc[e];
        if (z == 0) {
            __bf16* drow = cur_bf + (size_t)(i0 + r) * DD + d0 + c4;
            *(uint4*)drow = *(uint4*)&loc[0];
            *(uint4*)(drow + 8) = *(uint4*)&loc[8];
        }
        __syncthreads();
        alignas(16) unsigned short o[16];
#pragma unroll
        for (int e = 0; e < 16; ++e) o[e] = tile[c4 + e][r];
        __bf16* trow = dstT + (size_t)(d0 + r) * NN + i0 + c4;
        *(uint4*)trow = *(uint4*)&o[0];
        *(uint4*)(trow + 8) = *(uint4*)&o[8];
    } else {
        const int idx = bx - 512;
        const int m = idx >> 4, tt = idx & 15;
        const int k0 = (tt >> 2) * 64, n0 = (tt & 3) * 64;
        const float* src = m == 0 ? r_proj_s : m == 1 ? r_proj_t : m == 2 ? node_pj
                         : m == 3 ? spa_pj : m == 4 ? tmp_pj : theta_w;
        __bf16* dst = m == 0 ? pTs : m == 1 ? pTt : m == 2 ? pTn
                    : m == 3 ? pTspa : m == 4 ? pTtmp : thetaBf;
        const float* srow = src + (size_t)(k0 + r) * DD + n0 + c4;
        alignas(16) unsigned short loc[16];
#pragma unroll
        for (int e = 0; e < 4; ++e) {
            float4 v = ((const float4*)srow)[e];
            loc[e * 4 + 0] = bfbits(v.x); loc[e * 4 + 1] = bfbits(v.y);
            loc[e * 4 + 2] = bfbits(v.z); loc[e * 4 + 3] = bfbits(v.w);
        }
        if (m < 5) {
#pragma unroll
            for (int e = 0; e < 16; ++e) tile[r][c4 + e] = loc[e];
            __syncthreads();
            alignas(16) unsigned short o[16];
#pragma unroll
            for (int e = 0; e < 16; ++e) o[e] = tile[c4 + e][r];
            __bf16* trow = dst + (size_t)(n0 + r) * DD + k0 + c4;
            *(uint4*)trow = *(uint4*)&o[0];
            *(uint4*)(trow + 8) = *(uint4*)&o[8];
        } else {
            __bf16* drow = dst + (size_t)(k0 + r) * DD + n0 + c4;
            *(uint4*)drow = *(uint4*)&loc[0];
            *(uint4*)(drow + 8) = *(uint4*)&loc[8];
        }
    }
}

// =====================================================================================
// k_big: dual GEMM (raw + relu). 32m x 64n tiles, grid (4,128,2) = 1024 blocks = 4/CU.
// Reg-staged LDS (r3 structure), XOR-swizzled via pre-permuted global addresses.
// =====================================================================================
__global__ __launch_bounds__(256) void k_big(const __bf16* __restrict__ Mt, const __bf16* __restrict__ Ms,
                                             const __bf16* __restrict__ preT, const __bf16* __restrict__ curT,
                                             const float* __restrict__ negMt, const float* __restrict__ negMs,
                                             const float* __restrict__ cur,
                                             float* __restrict__ feaT, float* __restrict__ feaS,
                                             float* __restrict__ pDiff) {
    const int z = blockIdx.z;
    const __bf16* A  = z ? Ms : Mt;        // [4096][4096]
    const __bf16* BT = z ? curT : preT;    // [256][4096]
    const float* negM = z ? negMs : negMt;
    float* fea = z ? feaS : feaT;
    const int n0 = blockIdx.x * 64, m0 = blockIdx.y * 32;
    __shared__ __align__(16) __bf16 smA[32 * 64];   // 4 KB, swizzled 16B chunks
    __shared__ __align__(16) __bf16 smB[64 * 64];   // 8 KB
    __shared__ float sred[4];
    const int t = threadIdx.x, w = t >> 6, lane = t & 63, quad = lane >> 4, l16 = lane & 15;
    const int wr = w >> 1, wc = w & 1;

    // staging map: row = t>>3 (32 rows), chunk = t&7; global chunk pre-XOR-permuted
    const int srow = t >> 3, sc = t & 7;
    const int gsc = (sc ^ (srow & 7)) << 3;
    const __bf16* gA  = A  + (size_t)(m0 + srow) * NN + gsc;
    const __bf16* gB0 = BT + (size_t)(n0 + srow) * NN + gsc;
    const __bf16* gB1 = BT + (size_t)(n0 + srow + 32) * NN + gsc;
    __bf16* lA  = smA + srow * 64 + sc * 8;
    __bf16* lB0 = smB + srow * 64 + sc * 8;
    __bf16* lB1 = smB + (srow + 32) * 64 + sc * 8;

    f32x4 accR[2], accL[2];
#pragma unroll
    for (int nf = 0; nf < 2; ++nf) { accR[nf] = (f32x4)0.f; accL[nf] = (f32x4)0.f; }

    const int s7 = l16 & 7;
    const __bf16* arow  = smA + (wr * 16 + l16) * 64;
    const __bf16* brow0 = smB + (wc * 32 + l16) * 64;
    const __bf16* brow1 = smB + (wc * 32 + 16 + l16) * 64;

    for (int kt = 0; kt < 64; ++kt) {
        uint4 va  = *(const uint4*)(gA);
        uint4 vb0 = *(const uint4*)(gB0);
        uint4 vb1 = *(const uint4*)(gB1);
        gA += 64; gB0 += 64; gB1 += 64;
        __syncthreads();
        *(uint4*)lA = va; *(uint4*)lB0 = vb0; *(uint4*)lB1 = vb1;
        __syncthreads();
#pragma unroll
        for (int ks = 0; ks < 2; ++ks) {
            const int so = ((ks * 4 + quad) ^ s7) << 3;   // swizzled elem offset
            bf16x8 a  = *(const bf16x8*)(arow + so);
            bf16x8 b0 = *(const bf16x8*)(brow0 + so);
            bf16x8 b1 = *(const bf16x8*)(brow1 + so);
            bf16x8 ar = brelu(a);
            accR[0] = MFMA16(a, b0, accR[0]);
            accR[1] = MFMA16(a, b1, accR[1]);
            accL[0] = MFMA16(ar, b0, accL[0]);
            accL[1] = MFMA16(ar, b1, accL[1]);
        }
    }

    float sumd = 0.f;
#pragma unroll
    for (int nf = 0; nf < 2; ++nf)
#pragma unroll
        for (int r = 0; r < 4; ++r) {
            int gr = m0 + wr * 16 + quad * 4 + r;
            int gc = n0 + wc * 32 + nf * 16 + l16;
            size_t idx = (size_t)gr * DD + gc;
            float diff = accR[nf][r] + negM[idx];   // recon - master
            sumd += diff * diff;
            fea[idx] = accL[nf][r] + cur[idx];      // relu-product + cur
        }
    sumd = wave_red(sumd);
    if (lane == 0) sred[w] = sumd;
    __syncthreads();
    if (t == 0)
        pDiff[z * 512 + blockIdx.y * 4 + blockIdx.x] = sred[0] + sred[1] + sred[2] + sred[3];
}

// ---------------- shared MFMA inner step for the 64x64-tile small kernels ----------------
__device__ inline void mfma_step0(const __bf16 (*As)[72], const __bf16 (*Bs)[72],
                                  int wr, int wc, int quad, int l16, f32x4 (&acc)[2][2]) {
#pragma unroll
    for (int ks = 0; ks < 2; ++ks) {
        const int kc = ks * 32 + quad * 8;
        bf16x8 a0 = *(const bf16x8*)&As[wr * 32 + l16][kc];
        bf16x8 a1 = *(const bf16x8*)&As[wr * 32 + 16 + l16][kc];
        bf16x8 b0 = *(const bf16x8*)&Bs[wc * 32 + l16][kc];
        bf16x8 b1 = *(const bf16x8*)&Bs[wc * 32 + 16 + l16][kc];
        acc[0][0] = MFMA16(a0, b0, acc[0][0]);
        acc[0][1] = MFMA16(a0, b1, acc[0][1]);
        acc[1][0] = MFMA16(a1, b0, acc[1][0]);
        acc[1][1] = MFMA16(a1, b1, acc[1][1]);
    }
}

// ---------------- small GEMMs: -master_s, -master_t, node_fea ----------------
__global__ __launch_bounds__(256) void k_small3(const __bf16* __restrict__ cur_bf,
                                                const __bf16* __restrict__ pTs, const __bf16* __restrict__ pTt,
                                                const __bf16* __restrict__ pTn,
                                                float* __restrict__ negMs, float* __restrict__ negMt,
                                                float* __restrict__ nodeFea) {
    const int z = blockIdx.z;
    const __bf16* BT = z == 0 ? pTs : (z == 1 ? pTt : pTn);
    const int n0 = blockIdx.x * 64, m0 = blockIdx.y * 64;
    __shared__ __bf16 As[64][72], Bs[64][72];
    f32x4 acc[2][2];
#pragma unroll
    for (int i = 0; i < 2; ++i)
#pragma unroll
        for (int j = 0; j < 2; ++j) acc[i][j] = (f32x4)0.f;
    const int t = threadIdx.x, w = t >> 6, lane = t & 63, quad = lane >> 4, l16 = lane & 15;
    const int wr = w >> 1, wc = w & 1;
    const int sr = t >> 2, sc = (t & 3) * 16;
    const __bf16* gA = cur_bf + (size_t)(m0 + sr) * DD + sc;
    const __bf16* gB = BT + (size_t)(n0 + sr) * DD + sc;
    for (int kt = 0; kt < DD / 64; ++kt) {
        uint4 av0 = *(const uint4*)(gA);
        uint4 av1 = *(const uint4*)(gA + 8);
        uint4 bv0 = *(const uint4*)(gB);
        uint4 bv1 = *(const uint4*)(gB + 8);
        __syncthreads();
        *(uint4*)&As[sr][sc] = av0; *(uint4*)&As[sr][sc + 8] = av1;
        *(uint4*)&Bs[sr][sc] = bv0; *(uint4*)&Bs[sr][sc + 8] = bv1;
        __syncthreads();
        mfma_step0(As, Bs, wr, wc, quad, l16, acc);
        gA += 64; gB += 64;
    }
#pragma unroll
    for (int mi = 0; mi < 2; ++mi)
#pragma unroll
        for (int ni = 0; ni < 2; ++ni)
#pragma unroll
            for (int r = 0; r < 4; ++r) {
                int gr = m0 + wr * 32 + mi * 16 + quad * 4 + r;
                int gc = n0 + wc * 32 + ni * 16 + l16;
                size_t o = (size_t)gr * DD + gc;
                float v = acc[mi][ni][r];
                if (z == 0) negMs[o] = -v;
                else if (z == 1) negMt[o] = -v;
                else nodeFea[o] = v;
            }
}

// ---------------- edge-feature projections: spa_fea / tmp_fea ----------------
__global__ __launch_bounds__(256) void k_fea(const float* __restrict__ feaS, const float* __restrict__ feaT,
                                             const float* __restrict__ rsS, const float* __restrict__ rsT,
                                             const __bf16* __restrict__ pTspa, const __bf16* __restrict__ pTtmp,
                                             float* __restrict__ spaF, float* __restrict__ tmpF) {
    const int z = blockIdx.z;
    const float* fea = z ? feaT : feaS;
    const float* rs = z ? rsT : rsS;
    const __bf16* BT = z ? pTtmp : pTspa;
    float* outF = z ? tmpF : spaF;
    const int n0 = blockIdx.x * 64, m0 = blockIdx.y * 64;
    __shared__ __bf16 As[64][72], Bs[64][72];
    f32x4 acc[2][2];
#pragma unroll
    for (int i = 0; i < 2; ++i)
#pragma unroll
        for (int j = 0; j < 2; ++j) acc[i][j] = (f32x4)0.f;
    const int t = threadIdx.x, w = t >> 6, lane = t & 63, quad = lane >> 4, l16 = lane & 15;
    const int wr = w >> 1, wc = w & 1;
    const int sr = t >> 2, sc = (t & 3) * 16;
    const float inv = 1.f / (rs[m0 + sr] + 1.f);
    const float* gA = fea + (size_t)(m0 + sr) * DD + sc;
    const __bf16* gB = BT + (size_t)(n0 + sr) * DD + sc;
    for (int kt = 0; kt < DD / 64; ++kt) {
        __bf16 tmp[16];
#pragma unroll
        for (int e4 = 0; e4 < 4; ++e4) {
            float4 v = ((const float4*)gA)[e4];
            tmp[e4 * 4 + 0] = (__bf16)(v.x * inv);
            tmp[e4 * 4 + 1] = (__bf16)(v.y * inv);
            tmp[e4 * 4 + 2] = (__bf16)(v.z * inv);
            tmp[e4 * 4 + 3] = (__bf16)(v.w * inv);
        }
        uint4 bv0 = *(const uint4*)(gB);
        uint4 bv1 = *(const uint4*)(gB + 8);
        __syncthreads();
        *(uint4*)&As[sr][sc] = *(uint4*)&tmp[0]; *(uint4*)&As[sr][sc + 8] = *(uint4*)&tmp[8];
        *(uint4*)&Bs[sr][sc] = bv0; *(uint4*)&Bs[sr][sc + 8] = bv1;
        __syncthreads();
        mfma_step0(As, Bs, wr, wc, quad, l16, acc);
        gA += 64; gB += 64;
    }
#pragma unroll
    for (int mi = 0; mi < 2; ++mi)
#pragma unroll
        for (int ni = 0; ni < 2; ++ni)
#pragma unroll
            for (int r = 0; r < 4; ++r) {
                int gr = m0 + wr * 32 + mi * 16 + quad * 4 + r;
                int gc = n0 + wc * 32 + ni * 16 + l16;
                outF[(size_t)gr * DD + gc] = acc[mi][ni][r];
            }
}

// ---------------- attention scalars ----------------
__global__ __launch_bounds__(256) void k_attn(const float* __restrict__ spaF, const float* __restrict__ tmpF,
                                              const float* __restrict__ nodeF,
                                              float* __restrict__ spaA, float* __restrict__ tmpA) {
    const int t = threadIdx.x, w = t >> 6, lane = t & 63;
    const int i = blockIdx.x * 4 + w;
    const float4* sf = (const float4*)(spaF + (size_t)i * DD);
    const float4* tf = (const float4*)(tmpF + (size_t)i * DD);
    const float4* nf = (const float4*)(nodeF + (size_t)i * DD);
    float4 s = sf[lane], p = tf[lane], n = nf[lane];
    float ds = s.x * n.x + s.y * n.y + s.z * n.z + s.w * n.w;
    float dt = p.x * n.x + p.y * n.y + p.z * n.z + p.w * n.w;
    ds = wave_red(ds); dt = wave_red(dt);
    if (lane == 0) { spaA[i] = ds * 0.0625f; tmpA[i] = dt * 0.0625f; }  // 1/sqrt(256)
}

// ---------------- final: val @ theta_w^T + b, relu -> d_out ----------------
__global__ __launch_bounds__(256) void k_final(const float* __restrict__ spaF, const float* __restrict__ tmpF,
                                               const float* __restrict__ spaA, const float* __restrict__ tmpA,
                                               const __bf16* __restrict__ thetaBf, const float* __restrict__ thetaB,
                                               float* __restrict__ out) {
    const int n0 = blockIdx.x * 64, m0 = blockIdx.y * 64;
    __shared__ __bf16 As[64][72], Bs[64][72];
    f32x4 acc[2][2];
#pragma unroll
    for (int i = 0; i < 2; ++i)
#pragma unroll
        for (int j = 0; j < 2; ++j) acc[i][j] = (f32x4)0.f;
    const int t = threadIdx.x, w = t >> 6, lane = t & 63, quad = lane >> 4, l16 = lane & 15;
    const int wr = w >> 1, wc = w & 1;
    const int sr = t >> 2, sc = (t & 3) * 16;
    const float sa = spaA[m0 + sr], ta = tmpA[m0 + sr];
    const float* gS = spaF + (size_t)(m0 + sr) * DD + sc;
    const float* gT = tmpF + (size_t)(m0 + sr) * DD + sc;
    const __bf16* gB = thetaBf + (size_t)(n0 + sr) * DD + sc;
    for (int kt = 0; kt < DD / 64; ++kt) {
        __bf16 tmp[16];
#pragma unroll
        for (int e4 = 0; e4 < 4; ++e4) {
            float4 vs = ((const float4*)gS)[e4];
            float4 vt = ((const float4*)gT)[e4];
            tmp[e4 * 4 + 0] = (__bf16)(sa * vs.x + ta * vt.x);
            tmp[e4 * 4 + 1] = (__bf16)(sa * vs.y + ta * vt.y);
            tmp[e4 * 4 + 2] = (__bf16)(sa * vs.z + ta * vt.z);
            tmp[e4 * 4 + 3] = (__bf16)(sa * vs.w + ta * vt.w);
        }
        uint4 bv0 = *(const uint4*)(gB);
        uint4 bv1 = *(const uint4*)(gB + 8);
        __syncthreads();
        *(uint4*)&As[sr][sc] = *(uint4*)&tmp[0]; *(uint4*)&As[sr][sc + 8] = *(uint4*)&tmp[8];
        *(uint4*)&Bs[sr][sc] = bv0; *(uint4*)&Bs[sr][sc + 8] = bv1;
        __syncthreads();
        mfma_step0(As, Bs, wr, wc, quad, l16, acc);
        gS += 64; gT += 64; gB += 64;
    }
#pragma unroll
    for (int mi = 0; mi < 2; ++mi)
#pragma unroll
        for (int ni = 0; ni < 2; ++ni)
#pragma unroll
            for (int r = 0; r < 4; ++r) {
                int gr = m0 + wr * 32 + mi * 16 + quad * 4 + r;
                int gc = n0 + wc * 32 + ni * 16 + l16;
                float v = acc[mi][ni][r] + thetaB[gc];
                out[(size_t)gr * DD + gc] = fmaxf(v, 0.f);
            }
}

// ---------------- loss: reduce per-block partials, single block ----------------
__global__ __launch_bounds__(256) void k_loss(const float* __restrict__ pAbsT, const float* __restrict__ pSqT,
                                              const float* __restrict__ pAbsS, const float* __restrict__ pSqS,
                                              const float* __restrict__ pDiff,
                                              float* __restrict__ out) {
    const int t = threadIdx.x;
    float aT = 0.f, qT = 0.f, aS = 0.f, qS = 0.f;
#pragma unroll
    for (int j = 0; j < 16; ++j) {
        const int i = t + 256 * j;
        aT += pAbsT[i]; qT += pSqT[i]; aS += pAbsS[i]; qS += pSqS[i];
    }
    float dT = pDiff[t] + pDiff[256 + t];
    float dS = pDiff[512 + t] + pDiff[768 + t];
    aT = wave_red(aT); qT = wave_red(qT); aS = wave_red(aS); qS = wave_red(qS);
    dT = wave_red(dT); dS = wave_red(dS);
    __shared__ float red[6][4];
    const int w = t >> 6, lane = t & 63;
    if (lane == 0) { red[0][w] = aT; red[1][w] = qT; red[2][w] = aS; red[3][w] = qS; red[4][w] = dT; red[5][w] = dS; }
    __syncthreads();
    if (t == 0) {
        float s[6];
#pragma unroll
        for (int k = 0; k < 6; ++k) s[k] = red[k][0] + red[k][1] + red[k][2] + red[k][3];
        float l = s[0] + 0.001f * sqrtf(s[1]) + 0.2f * sqrtf(s[4])    // temporal
                + s[2] + 0.001f * sqrtf(s[3]) + 0.2f * sqrtf(s[5]);   // spatial
        out[(size_t)NN * DD] = l;
    }
}

extern "C" void kernel_launch(void* const* d_in, const int* in_sizes, int n_in,
                              void* d_out, int out_size, void* d_ws, size_t ws_size,
                              hipStream_t stream) {
    (void)in_sizes; (void)n_in; (void)out_size; (void)ws_size;
    const float* cur      = (const float*)d_in[0];
    const float* pre      = (const float*)d_in[1];
    const float* r_proj_s = (const float*)d_in[2];
    const float* inc_s    = (const float*)d_in[3];
    const float* r_proj_t = (const float*)d_in[4];
    const float* inc_t    = (const float*)d_in[5];
    const float* node_pj  = (const float*)d_in[6];
    const float* spa_pj   = (const float*)d_in[7];
    const float* tmp_pj   = (const float*)d_in[8];
    const float* theta_w  = (const float*)d_in[9];
    const float* theta_b  = (const float*)d_in[10];
    float* out = (float*)d_out;

    char* p = (char*)d_ws;
    auto alloc = [&](size_t bytes) -> void* {
        void* r = (void*)p;
        p += (bytes + 255) & ~(size_t)255;
        return r;
    };
    __bf16* Mt      = (__bf16*)alloc((size_t)NN * NN * 2);
    __bf16* Ms      = (__bf16*)alloc((size_t)NN * NN * 2);
    __bf16* cur_bf  = (__bf16*)alloc((size_t)NN * DD * 2);
    __bf16* curT    = (__bf16*)alloc((size_t)NN * DD * 2);
    __bf16* preT    = (__bf16*)alloc((size_t)NN * DD * 2);
    __bf16* pTs     = (__bf16*)alloc((size_t)DD * DD * 2);
    __bf16* pTt     = (__bf16*)alloc((size_t)DD * DD * 2);
    __bf16* pTn     = (__bf16*)alloc((size_t)DD * DD * 2);
    __bf16* pTspa   = (__bf16*)alloc((size_t)DD * DD * 2);
    __bf16* pTtmp   = (__bf16*)alloc((size_t)DD * DD * 2);
    __bf16* thetaBf = (__bf16*)alloc((size_t)DD * DD * 2);
    float* negMs    = (float*)alloc((size_t)NN * DD * 4);
    float* negMt    = (float*)alloc((size_t)NN * DD * 4);
    float* nodeFea  = (float*)alloc((size_t)NN * DD * 4);
    float* feaS     = (float*)alloc((size_t)NN * DD * 4);
    float* feaT     = (float*)alloc((size_t)NN * DD * 4);
    float* spaF     = (float*)alloc((size_t)NN * DD * 4);
    float* tmpF     = (float*)alloc((size_t)NN * DD * 4);
    float* rsS      = (float*)alloc((size_t)NN * 4);
    float* rsT      = (float*)alloc((size_t)NN * 4);
    float* spaA     = (float*)alloc((size_t)NN * 4);
    float* tmpA     = (float*)alloc((size_t)NN * 4);
    float* pAbsT    = (float*)alloc((size_t)NN * 4);
    float* pSqT     = (float*)alloc((size_t)NN * 4);
    float* pAbsS    = (float*)alloc((size_t)NN * 4);
    float* pSqS     = (float*)alloc((size_t)NN * 4);
    float* pDiff    = (float*)alloc(1024 * 4);

    k_conv_t<<<NN, 256, 0, stream>>>(inc_t, Mt, rsT, pAbsT, pSqT);
    k_conv_s<<<NN, 256, 0, stream>>>(inc_s, Ms, rsS, pAbsS, pSqS);
    k_misc<<<608, 256, 0, stream>>>(cur, pre, r_proj_s, r_proj_t, node_pj, spa_pj, tmp_pj, theta_w,
                                    cur_bf, curT, preT, pTs, pTt, pTn, pTspa, pTtmp, thetaBf);
    k_small3<<<dim3(4, 64, 3), 256, 0, stream>>>(cur_bf, pTs, pTt, pTn, negMs, negMt, nodeFea);
    k_big<<<dim3(4, 128, 2), 256, 0, stream>>>(Mt, Ms, preT, curT, negMt, negMs, cur, feaT, feaS, pDiff);
    k_fea<<<dim3(4, 64, 2), 256, 0, stream>>>(feaS, feaT, rsS, rsT, pTspa, pTtmp, spaF, tmpF);
    k_attn<<<NN / 4, 256, 0, stream>>>(spaF, tmpF, nodeFea, spaA, tmpA);
    k_final<<<dim3(4, 64), 256, 0, stream>>>(spaF, tmpF, spaA, tmpA, thetaBf, theta_b, out);
    k_loss<<<1, 256, 0, stream>>>(pAbsT, pSqT, pAbsS, pSqS, pDiff, out);
}